// Round 1
// baseline (18.894 us; speedup 1.0000x reference)
//
#include <hip/hip_runtime.h>

// Problem constants (B,C,H,W,L) = (4,16,256,256,25)
#define HWPIX 65536   // H*W
#define NCH   16
#define NLBL  25

// LDS weight layout: w2[k][l] holds (weight[l][2k], weight[l][2k+1]) where the
// flat in-matrix index is o*16+c, so k = o*8 + c/2.  Bank of w2[k][l] is
// (k*64 + 2l) % 32 = 2l % 32 -> distinct labels hit distinct bank-pairs except
// (l, l+16): a 2-way conflict (free).  Same-label lanes broadcast.
__global__ __launch_bounds__(256) void invconv_kernel(
    const float* __restrict__ x,
    const int*   __restrict__ labels,
    const float* __restrict__ weight,
    const float* __restrict__ bias,
    float*       __restrict__ out)
{
    __shared__ float2 w2[128][32];   // 32 KiB

    const int tid = threadIdx.x;

    // Stage weights: flat = k*32 + l, consecutive threads take consecutive l
    // (spread across banks on the ds_write side too).
    #pragma unroll
    for (int i = 0; i < 16; ++i) {
        int flat = tid + i * 256;        // < 4096
        int l = flat & 31;
        int k = flat >> 5;               // 0..127
        if (l < NLBL) {
            w2[k][l] = *reinterpret_cast<const float2*>(weight + l * 256 + k * 2);
        }
    }
    __syncthreads();

    // Each thread handles 2 consecutive pixels (same batch: HW is a multiple of 2).
    const int t = blockIdx.x * 256 + tid;
    const int P = t * 2;                 // global pixel index, < B*H*W = 262144
    const int b = P >> 16;               // / HWPIX
    const int p = P & 65535;             // % HWPIX

    const int2 lab = *reinterpret_cast<const int2*>(labels + b * HWPIX + p);
    const int l0 = lab.x, l1 = lab.y;
    const float bias0 = bias[l0];
    const float bias1 = bias[l1];

    // Load x: 16 channels, one float2 (pixel pair) each -- coalesced 8B/lane.
    float2 xv[NCH];
    const float* xb = x + b * (NCH * HWPIX) + p;
    #pragma unroll
    for (int c = 0; c < NCH; ++c)
        xv[c] = *reinterpret_cast<const float2*>(xb + c * HWPIX);

    float* ob = out + b * (NCH * HWPIX) + p;
    #pragma unroll
    for (int o = 0; o < NCH; ++o) {
        float acc0 = bias0;
        float acc1 = bias1;
        #pragma unroll
        for (int c2 = 0; c2 < 8; ++c2) {
            const float2 wa = w2[o * 8 + c2][l0];
            const float2 wb = w2[o * 8 + c2][l1];
            const float2 xlo = xv[2 * c2];
            const float2 xhi = xv[2 * c2 + 1];
            acc0 += wa.x * xlo.x + wa.y * xhi.x;
            acc1 += wb.x * xlo.y + wb.y * xhi.y;
        }
        *reinterpret_cast<float2*>(ob + o * HWPIX) = make_float2(acc0, acc1);
    }
}

extern "C" void kernel_launch(void* const* d_in, const int* in_sizes, int n_in,
                              void* d_out, int out_size, void* d_ws, size_t ws_size,
                              hipStream_t stream) {
    const float* x      = (const float*)d_in[0];
    const int*   labels = (const int*)  d_in[1];
    const float* weight = (const float*)d_in[2];
    const float* bias   = (const float*)d_in[3];
    float*       out    = (float*)d_out;

    // total pixels = 4*256*256 = 262144; 2 px/thread, 256 threads/block
    dim3 grid(512), block(256);
    invconv_kernel<<<grid, block, 0, stream>>>(x, labels, weight, bias, out);
}